// Round 5
// 602.611 us; speedup vs baseline: 1.0878x; 1.0878x over previous
//
#include <hip/hip_runtime.h>
#include <hip/hip_bf16.h>
#include <math.h>

#define D 256
#define D4 64       // D / 4
#define GS 264      // bf16 LDS row stride: 16B-aligned rows (528B), canonical bank spread

typedef __attribute__((ext_vector_type(8))) short bf16x8;
typedef __attribute__((ext_vector_type(4))) float f32x4;

__device__ inline unsigned short f2bf(float f) {
    union { float f; unsigned u; } v; v.f = f;
    unsigned r = v.u + 0x7fffu + ((v.u >> 16) & 1u);   // RNE
    return (unsigned short)(r >> 16);
}
__device__ inline float bf2f(unsigned short u) {
    union { unsigned u; float f; } v; v.u = ((unsigned)u) << 16; return v.f;
}
__device__ inline float gelu_tanh(float t) {
    float z = 0.7978845608028654f * (t + 0.044715f * t * t * t);
    float e = __expf(2.f * z);
    return 0.5f * t * (2.f - 2.f / (e + 1.f));
}
// nontemporal float4 load: builtin requires scalar/ext-vector pointee, so cast
// the HIP_vector_type pointer to the clang ext_vector type f32x4.
__device__ inline f32x4 ntload4(const float4* p) {
    return __builtin_nontemporal_load((const f32x4*)p);
}

// W1,W2 -> bf16; fold BN params; zero histogram counters
__global__ __launch_bounds__(256) void k_prep(
    const float* __restrict__ W1, const float* __restrict__ W2,
    unsigned short* __restrict__ W1b, unsigned short* __restrict__ W2b,
    const float* g1, const float* be1, const float* m1, const float* v1,
    const float* g2, const float* be2, const float* m2, const float* v2,
    float* s1, float* sh1, float* r1, float* s2, float* sh2,
    int* counts, int N_)
{
    int i = blockIdx.x * 256 + threadIdx.x;
    if (i < D * D) {
        W1b[i] = f2bf(W1[i]);
        W2b[i] = f2bf(W2[i]);
    }
    if (i < N_) counts[i] = 0;
    if (i < D) {
        float sc1 = g1[i] * rsqrtf(v1[i] + 1e-5f);
        s1[i] = sc1; sh1[i] = be1[i] - m1[i] * sc1; r1[i] = 1.f / sc1;
        float sc2 = g2[i] * rsqrtf(v2[i] + 1e-5f);
        s2[i] = sc2; sh2[i] = be2[i] - m2[i] * sc2;
    }
}

// ---- counting sort of edges by dst ----
__global__ __launch_bounds__(256) void k_hist(const int* __restrict__ ei, int* counts, int E_) {
    int e = blockIdx.x * 256 + threadIdx.x;
    if (e < E_) atomicAdd(&counts[ei[E_ + e]], 1);
}

__global__ __launch_bounds__(256) void k_scan1(const int* __restrict__ counts,
                                               int* offs, int* partials, int n) {
    __shared__ int tmp[256];
    int tid = threadIdx.x, i = blockIdx.x * 256 + tid;
    int v = (i < n) ? counts[i] : 0;
    tmp[tid] = v; __syncthreads();
    for (int d = 1; d < 256; d <<= 1) {
        int t = (tid >= d) ? tmp[tid - d] : 0;
        __syncthreads();
        tmp[tid] += t;
        __syncthreads();
    }
    if (i < n) offs[i] = tmp[tid] - v;          // exclusive
    if (tid == 255) partials[blockIdx.x] = tmp[255];
}

// merged scan2+scan3: each block reduces the raw partials below it into its
// prefix (nb<=~200, one coalesced pass + tree reduce), then adds and seeds cursor
__global__ __launch_bounds__(256) void k_scan23(int* offs, int* cursor,
                                                const int* __restrict__ partials,
                                                int nb, int n, int E_) {
    __shared__ int red[256];
    int tid = threadIdx.x;
    int v = 0;
    for (int t = tid; t < nb; t += 256)
        if (t < (int)blockIdx.x) v += partials[t];
    red[tid] = v; __syncthreads();
    for (int d = 128; d > 0; d >>= 1) {
        if (tid < d) red[tid] += red[tid + d];
        __syncthreads();
    }
    int prefix = red[0];
    int i = blockIdx.x * 256 + tid;
    if (i < n) {
        int val = offs[i] + prefix;
        offs[i] = val;
        cursor[i] = val;
    }
    if (i == 0) offs[n] = E_;
}

// sorted[pos] = {src, edge_id}
__global__ __launch_bounds__(256) void k_bucket(const int* __restrict__ ei,
                                                int* cursor, int2* sorted, int E_) {
    int e = blockIdx.x * 256 + threadIdx.x;
    if (e < E_) {
        int d = ei[E_ + e];
        int pos = atomicAdd(&cursor[d], 1);
        sorted[pos] = make_int2(ei[e], e);
    }
}

// ---- fully fused: aggregation (gather, no atomics) + BN1 -> LDS bf16 tile
//      -> GEMM1 -> GELU -> LDS -> GEMM2 -> residual + BN2 -> out
// Block = 4 waves = one 16-row tile. LDS 16.9 KB.
// Phase 1 is latency-critical: edge list is fetched ONCE per row as a
// lane-parallel 512B chunk (shfl-broadcast per edge), and the x/ea data
// loads are unrolled 4x so ~8KB/wave is in flight -> BW-bound, not
// dependent-chain-bound.
__global__ __launch_bounds__(256) void k_fused(
    const float4* __restrict__ x, const float4* __restrict__ ea,
    const int* __restrict__ offs, const int2* __restrict__ sorted,
    const float* __restrict__ s1, const float* __restrict__ sh1,
    const float* __restrict__ r1,
    const unsigned short* __restrict__ W1, const unsigned short* __restrict__ W2,
    const float* __restrict__ b1, const float* __restrict__ b2,
    const float* __restrict__ s2, const float* __restrict__ sh2,
    float* __restrict__ out, int M)
{
    __shared__ __align__(16) unsigned short As[16][GS];  // bf16(BN1(h)) tile
    __shared__ __align__(16) unsigned short Gsm[16][GS]; // bf16(gelu) tile

    int wave = threadIdx.x >> 6, lane = threadIdx.x & 63;
    int m_base = blockIdx.x * 16;

    // ---- phase 1: aggregate 4 rows per wave ----
    float4 sc1v = ((const float4*)s1)[lane];
    float4 sh1v = ((const float4*)sh1)[lane];
#pragma unroll
    for (int rr = 0; rr < 4; ++rr) {
        int tr = wave * 4 + rr;
        int row = m_base + tr;
        if (row < M) {
            float4 xv = x[(long)row * D4 + lane];
            float ax = 2.f * xv.x, ay = 2.f * xv.y, az = 2.f * xv.z, aw = 2.f * xv.w;
            int b = offs[row], en = offs[row + 1];
            int done = b;
            while (done < en) {
                int rem = en - done;
                int chunk = rem < 64 ? rem : 64;
                int lidx = lane < chunk ? lane : chunk - 1;
                int2 se = sorted[done + lidx];   // whole edge chunk in one 512B load
                int j = 0;
                for (; j + 4 <= chunk; j += 4) {
                    int p0 = __shfl(se.x, j    ), q0 = __shfl(se.y, j    );
                    int p1 = __shfl(se.x, j + 1), q1 = __shfl(se.y, j + 1);
                    int p2 = __shfl(se.x, j + 2), q2 = __shfl(se.y, j + 2);
                    int p3 = __shfl(se.x, j + 3), q3 = __shfl(se.y, j + 3);
                    float4 s0 = x[(long)p0 * D4 + lane];
                    f32x4  a0 = ntload4(&ea[(long)q0 * D4 + lane]);
                    float4 s1v = x[(long)p1 * D4 + lane];
                    f32x4  a1 = ntload4(&ea[(long)q1 * D4 + lane]);
                    float4 s2v = x[(long)p2 * D4 + lane];
                    f32x4  a2 = ntload4(&ea[(long)q2 * D4 + lane]);
                    float4 s3v = x[(long)p3 * D4 + lane];
                    f32x4  a3 = ntload4(&ea[(long)q3 * D4 + lane]);
                    ax += fmaxf(s0.x + a0.x, 0.f) + fmaxf(s1v.x + a1.x, 0.f)
                        + fmaxf(s2v.x + a2.x, 0.f) + fmaxf(s3v.x + a3.x, 0.f);
                    ay += fmaxf(s0.y + a0.y, 0.f) + fmaxf(s1v.y + a1.y, 0.f)
                        + fmaxf(s2v.y + a2.y, 0.f) + fmaxf(s3v.y + a3.y, 0.f);
                    az += fmaxf(s0.z + a0.z, 0.f) + fmaxf(s1v.z + a1.z, 0.f)
                        + fmaxf(s2v.z + a2.z, 0.f) + fmaxf(s3v.z + a3.z, 0.f);
                    aw += fmaxf(s0.w + a0.w, 0.f) + fmaxf(s1v.w + a1.w, 0.f)
                        + fmaxf(s2v.w + a2.w, 0.f) + fmaxf(s3v.w + a3.w, 0.f);
                }
                for (; j + 2 <= chunk; j += 2) {
                    int p0 = __shfl(se.x, j    ), q0 = __shfl(se.y, j    );
                    int p1 = __shfl(se.x, j + 1), q1 = __shfl(se.y, j + 1);
                    float4 s0 = x[(long)p0 * D4 + lane];
                    f32x4  a0 = ntload4(&ea[(long)q0 * D4 + lane]);
                    float4 s1v = x[(long)p1 * D4 + lane];
                    f32x4  a1 = ntload4(&ea[(long)q1 * D4 + lane]);
                    ax += fmaxf(s0.x + a0.x, 0.f) + fmaxf(s1v.x + a1.x, 0.f);
                    ay += fmaxf(s0.y + a0.y, 0.f) + fmaxf(s1v.y + a1.y, 0.f);
                    az += fmaxf(s0.z + a0.z, 0.f) + fmaxf(s1v.z + a1.z, 0.f);
                    aw += fmaxf(s0.w + a0.w, 0.f) + fmaxf(s1v.w + a1.w, 0.f);
                }
                if (j < chunk) {
                    int p0 = __shfl(se.x, j), q0 = __shfl(se.y, j);
                    float4 s0 = x[(long)p0 * D4 + lane];
                    f32x4  a0 = ntload4(&ea[(long)q0 * D4 + lane]);
                    ax += fmaxf(s0.x + a0.x, 0.f);
                    ay += fmaxf(s0.y + a0.y, 0.f);
                    az += fmaxf(s0.z + a0.z, 0.f);
                    aw += fmaxf(s0.w + a0.w, 0.f);
                }
                done += chunk;
            }
            ushort4 o;
            o.x = f2bf(ax * sc1v.x + sh1v.x);
            o.y = f2bf(ay * sc1v.y + sh1v.y);
            o.z = f2bf(az * sc1v.z + sh1v.z);
            o.w = f2bf(aw * sc1v.w + sh1v.w);
            *(ushort4*)&As[tr][lane * 4] = o;
        }
    }
    __syncthreads();

    int l16 = lane & 15, quad = lane >> 4;

    // A-frags from LDS (A[m=l16][k=quad*8 + s*32 + j])
    bf16x8 frag[8];
#pragma unroll
    for (int s = 0; s < 8; ++s)
        frag[s] = *(const bf16x8*)&As[l16][quad * 8 + s * 32];

    // ---- phase 2: GEMM1 + GELU -> Gsm; wave handles n-tiles wave*4..wave*4+3 ----
#pragma unroll
    for (int t = 0; t < 4; ++t) {
        int ncol = (wave * 4 + t) * 16 + l16;
        const bf16x8* Wrow = (const bf16x8*)(W1 + ((long)ncol * D + quad * 8));
        f32x4 acc0 = {0.f, 0.f, 0.f, 0.f};
        f32x4 acc1 = {0.f, 0.f, 0.f, 0.f};
#pragma unroll
        for (int s = 0; s < 8; s += 2) {
            acc0 = __builtin_amdgcn_mfma_f32_16x16x32_bf16(frag[s],     Wrow[s * 4],       acc0, 0, 0, 0);
            acc1 = __builtin_amdgcn_mfma_f32_16x16x32_bf16(frag[s + 1], Wrow[(s + 1) * 4], acc1, 0, 0, 0);
        }
        float b = b1[ncol];
#pragma unroll
        for (int r = 0; r < 4; ++r) {
            float v = acc0[r] + acc1[r] + b;
            Gsm[quad * 4 + r][ncol] = f2bf(gelu_tanh(v));
        }
    }
    __syncthreads();

#pragma unroll
    for (int s = 0; s < 8; ++s)
        frag[s] = *(const bf16x8*)&Gsm[l16][quad * 8 + s * 32];

    // ---- phase 3: GEMM2 + residual + BN2 ----
#pragma unroll
    for (int t = 0; t < 4; ++t) {
        int ncol = (wave * 4 + t) * 16 + l16;
        const bf16x8* Wrow = (const bf16x8*)(W2 + ((long)ncol * D + quad * 8));
        f32x4 acc0 = {0.f, 0.f, 0.f, 0.f};
        f32x4 acc1 = {0.f, 0.f, 0.f, 0.f};
#pragma unroll
        for (int s = 0; s < 8; s += 2) {
            acc0 = __builtin_amdgcn_mfma_f32_16x16x32_bf16(frag[s],     Wrow[s * 4],       acc0, 0, 0, 0);
            acc1 = __builtin_amdgcn_mfma_f32_16x16x32_bf16(frag[s + 1], Wrow[(s + 1) * 4], acc1, 0, 0, 0);
        }
        float b = b2[ncol], rr1 = r1[ncol], sh = sh1[ncol];
        float c2 = s2[ncol], h2 = sh2[ncol];
#pragma unroll
        for (int r = 0; r < 4; ++r) {
            int tr = quad * 4 + r;
            int row = m_base + tr;
            if (row < M) {
                float f = acc0[r] + acc1[r] + b;
                float hv = (bf2f(As[tr][ncol]) - sh) * rr1;   // h from LDS bf16 tile
                __builtin_nontemporal_store((hv + f) * c2 + h2, &out[(long)row * D + ncol]);
            }
        }
    }
}

extern "C" void kernel_launch(void* const* d_in, const int* in_sizes, int n_in,
                              void* d_out, int out_size, void* d_ws, size_t ws_size,
                              hipStream_t stream) {
    const float* x   = (const float*)d_in[0];
    const int*   ei  = (const int*)d_in[1];
    const float* ea  = (const float*)d_in[2];
    const float* W1  = (const float*)d_in[3];
    const float* b1  = (const float*)d_in[4];
    const float* W2  = (const float*)d_in[5];
    const float* b2  = (const float*)d_in[6];
    const float* g1  = (const float*)d_in[7];
    const float* be1 = (const float*)d_in[8];
    const float* m1  = (const float*)d_in[9];
    const float* v1  = (const float*)d_in[10];
    const float* g2  = (const float*)d_in[11];
    const float* be2 = (const float*)d_in[12];
    const float* m2  = (const float*)d_in[13];
    const float* v2  = (const float*)d_in[14];
    float* out = (float*)d_out;

    int N_ = in_sizes[0] / D;
    int E_ = in_sizes[2] / D;

    char* ws = (char*)d_ws;
    size_t off = 0;
    unsigned short* W1b = (unsigned short*)(ws + off);  off += (size_t)D * D * 2;
    unsigned short* W2b = (unsigned short*)(ws + off);  off += (size_t)D * D * 2;
    float* s1  = (float*)(ws + off); off += D * 4;
    float* sh1 = (float*)(ws + off); off += D * 4;
    float* r1  = (float*)(ws + off); off += D * 4;
    float* s2  = (float*)(ws + off); off += D * 4;
    float* sh2 = (float*)(ws + off); off += D * 4;
    int* counts   = (int*)(ws + off); off += (size_t)N_ * 4;
    int* cursor   = (int*)(ws + off); off += (size_t)N_ * 4;
    int* offs     = (int*)(ws + off); off += (size_t)(N_ + 1) * 4;
    int* partials = (int*)(ws + off); off += 256 * 4;
    int2* sorted  = (int2*)(ws + off); off += (size_t)E_ * 8;

    int nblkN = (N_ + 255) / 256;
    int nblkE = (E_ + 255) / 256;

    k_prep<<<(D * D + 255) / 256, 256, 0, stream>>>(W1, W2, W1b, W2b,
        g1, be1, m1, v1, g2, be2, m2, v2, s1, sh1, r1, s2, sh2, counts, N_);
    k_hist<<<nblkE, 256, 0, stream>>>(ei, counts, E_);
    k_scan1<<<nblkN, 256, 0, stream>>>(counts, offs, partials, N_);
    k_scan23<<<nblkN, 256, 0, stream>>>(offs, cursor, partials, nblkN, N_, E_);
    k_bucket<<<nblkE, 256, 0, stream>>>(ei, cursor, sorted, E_);

    int mtiles = (N_ + 15) / 16;
    k_fused<<<mtiles, 256, 0, stream>>>((const float4*)x, (const float4*)ea,
        offs, sorted, s1, sh1, r1, W1b, W2b, b1, b2, s2, sh2, out, N_);
}